// Round 1
// baseline (1126.408 us; speedup 1.0000x reference)
//
#include <hip/hip_runtime.h>
#include <stdint.h>

typedef float f32x4 __attribute__((ext_vector_type(4)));
typedef short s16x8 __attribute__((ext_vector_type(8)));
typedef short s16x4 __attribute__((ext_vector_type(4)));

#define HDIM 128
#define TLEN 512
#define BT 16

__device__ __forceinline__ unsigned short f2bf(float f) {
    union { float f; uint32_t u; } v; v.f = f;
    uint32_t r = v.u + 0x7FFFu + ((v.u >> 16) & 1u);
    return (unsigned short)(r >> 16);
}
__device__ __forceinline__ float bfhi(uint32_t u){ union{uint32_t u;float f;}v; v.u = u & 0xFFFF0000u; return v.f; }
__device__ __forceinline__ float bflo(uint32_t u){ union{uint32_t u;float f;}v; v.u = u << 16; return v.f; }

__device__ __forceinline__ float sigmoidf_(float x){
    float e = __expf(-x);
    return __builtin_amdgcn_rcpf(1.0f + e);
}
__device__ __forceinline__ float tanhf_(float x){
    float e = __expf(2.0f * x);            // x>>0: e=inf -> rcp=0 -> 1 ; x<<0: e=0 -> -1
    return 1.0f - 2.0f * __builtin_amdgcn_rcpf(1.0f + e);
}

__global__ __launch_bounds__(512, 2) void lstm_fused_kernel(
    const float* __restrict__ x,      // (2048,512,1)
    const float* __restrict__ Wih0,   // (512,1)
    const float* __restrict__ Whh0,   // (512,128)
    const float* __restrict__ bih0,
    const float* __restrict__ bhh0,
    const float* __restrict__ Wih1,   // (512,128)
    const float* __restrict__ Whh1,   // (512,128)
    const float* __restrict__ bih1,
    const float* __restrict__ bhh1,
    const float* __restrict__ W1,     // (64,128)
    const float* __restrict__ b1,     // (64)
    const float* __restrict__ W2,     // (8,64)
    const float* __restrict__ b2,     // (8)
    float* __restrict__ out)          // (2048,8)
{
    // LDS: W_hh0 in MFMA-fragment order (128KB) + h fragments + x tile
    __shared__ __align__(16) short w0lds[65536];   // [c][w][tile][lane] * 8 shorts
    __shared__ __align__(16) short h0frag[2048];   // [c][lane] * 8 shorts (B-frag order)
    __shared__ __align__(16) short h1frag[2048];
    __shared__ __align__(16) float xlds[64 * 16];  // [t&63][n]

    const int tid = threadIdx.x;
    const int w = tid >> 6;     // wave 0..7 ; owns units [16w,16w+16)
    const int l = tid & 63;
    const int n = l & 15;       // batch col (B-operand) / row-in-tile (A-operand)
    const int q = l >> 4;       // k-group
    const int b0 = blockIdx.x * BT;

    // ---- W_ih1 / W_hh1 fragments into registers (bf16), [kchunk][tile] ----
    s16x8 wi1f[4][4], wh1f[4][4];
    #pragma unroll
    for (int c = 0; c < 4; ++c) {
        #pragma unroll
        for (int tile = 0; tile < 4; ++tile) {
            int g  = tile * 128 + w * 16 + n;       // gate row
            int k0 = c * 32 + q * 8;
            const float* p1 = Wih1 + g * HDIM + k0;
            const float* p2 = Whh1 + g * HDIM + k0;
            s16x8 a, b;
            #pragma unroll
            for (int j = 0; j < 8; ++j) { a[j] = (short)f2bf(p1[j]); b[j] = (short)f2bf(p2[j]); }
            wi1f[c][tile] = a; wh1f[c][tile] = b;
        }
    }

    // ---- W_hh0 into LDS, fragment-ordered ----
    for (int s = tid; s < 8192; s += 512) {
        int ll = s & 63, tl = (s >> 6) & 3, ww = (s >> 8) & 7, cc = s >> 11;
        int g  = tl * 128 + ww * 16 + (ll & 15);
        int k0 = cc * 32 + (ll >> 4) * 8;
        const float* p = Whh0 + g * HDIM + k0;
        s16x8 a;
        #pragma unroll
        for (int j = 0; j < 8; ++j) a[j] = (short)f2bf(p[j]);
        *(s16x8*)&w0lds[s * 8] = a;
    }

    // ---- per-lane constants: packed-bf16 biases + x-weight ----
    const int u0 = w * 16 + q * 4;          // first of this lane's 4 units
    uint32_t b0p[8], b1p[8], wxp[8];
    #pragma unroll
    for (int i = 0; i < 8; ++i) {
        int tr0 = 2 * i;
        int tile = tr0 >> 2, r0 = tr0 & 3;
        int g0 = tile * 128 + u0 + r0;
        int g1 = g0 + 1;
        b0p[i] = ((uint32_t)f2bf(bih0[g1] + bhh0[g1]) << 16) | f2bf(bih0[g0] + bhh0[g0]);
        b1p[i] = ((uint32_t)f2bf(bih1[g1] + bhh1[g1]) << 16) | f2bf(bih1[g0] + bhh1[g0]);
        wxp[i] = ((uint32_t)f2bf(Wih0[g1]) << 16) | f2bf(Wih0[g0]);
    }

    // zero h fragments (h_{-1} = 0)
    for (int s = tid; s < 1024; s += 512) {
        ((uint32_t*)h0frag)[s] = 0u;
        ((uint32_t*)h1frag)[s] = 0u;
    }

    // B-fragment write slot for this lane's 4 units (consecutive j)
    const int cp  = u0 >> 5;
    const int kbp = (u0 >> 3) & 3;
    const int j0  = u0 & 7;                 // 0 or 4
    const int fragoff = (cp * 64 + (n + 16 * kbp)) * 8 + j0;   // short index

    float c0v[4] = {0.f, 0.f, 0.f, 0.f};
    float c1v[4] = {0.f, 0.f, 0.f, 0.f};
    float hfin[4] = {0.f, 0.f, 0.f, 0.f};

    __syncthreads();

    #pragma unroll 1
    for (int t = 0; t < TLEN; ++t) {
        if ((t & 63) == 0) {
            // refill x tile (old-chunk readers are all past prior barriers)
            #pragma unroll
            for (int i2 = 0; i2 < 2; ++i2) {
                int idx = tid + i2 * 512;
                int tt = idx & 63, nn = idx >> 6;
                xlds[tt * 16 + nn] = x[(size_t)(b0 + nn) * TLEN + t + tt];
            }
            __syncthreads();
        }

        // ---- phase 1: gates0 = bias0 + Wih0*x_t + Whh0 @ h0[t-1] ----
        float xv = xlds[(t & 63) * 16 + n];
        f32x4 acc[4];
        #pragma unroll
        for (int tile = 0; tile < 4; ++tile) {
            #pragma unroll
            for (int r = 0; r < 4; ++r) {
                int tr = tile * 4 + r;
                float bb = (tr & 1) ? bfhi(b0p[tr >> 1]) : bflo(b0p[tr >> 1]);
                float wwv = (tr & 1) ? bfhi(wxp[tr >> 1]) : bflo(wxp[tr >> 1]);
                acc[tile][r] = bb + wwv * xv;
            }
        }
        #pragma unroll
        for (int c = 0; c < 4; ++c) {
            s16x8 hb = *(const s16x8*)&h0frag[(c * 64 + l) * 8];
            #pragma unroll
            for (int tile = 0; tile < 4; ++tile) {
                s16x8 a = *(const s16x8*)&w0lds[(((c * 8 + w) * 4 + tile) * 64 + l) * 8];
                acc[tile] = __builtin_amdgcn_mfma_f32_16x16x32_bf16(a, hb, acc[tile], 0, 0, 0);
            }
        }
        __syncthreads();   // phase1 reads of h0frag done

        // ---- phase 2: layer-0 pointwise update (lane-local) ----
        {
            s16x4 hw;
            #pragma unroll
            for (int r = 0; r < 4; ++r) {
                float ig = sigmoidf_(acc[0][r]);
                float fg = sigmoidf_(acc[1][r]);
                float gg = tanhf_(acc[2][r]);
                float og = sigmoidf_(acc[3][r]);
                float cc = fg * c0v[r] + ig * gg;
                c0v[r] = cc;
                float hh = og * tanhf_(cc);
                hw[r] = (short)f2bf(hh);
            }
            *(s16x4*)&h0frag[fragoff] = hw;
        }
        __syncthreads();   // h0frag[t] visible

        // ---- phase 3: gates1 = bias1 + Wih1 @ h0[t] + Whh1 @ h1[t-1] ----
        #pragma unroll
        for (int tile = 0; tile < 4; ++tile) {
            #pragma unroll
            for (int r = 0; r < 4; ++r) {
                int tr = tile * 4 + r;
                acc[tile][r] = (tr & 1) ? bfhi(b1p[tr >> 1]) : bflo(b1p[tr >> 1]);
            }
        }
        #pragma unroll
        for (int c = 0; c < 4; ++c) {
            s16x8 hb0 = *(const s16x8*)&h0frag[(c * 64 + l) * 8];
            s16x8 hb1 = *(const s16x8*)&h1frag[(c * 64 + l) * 8];
            #pragma unroll
            for (int tile = 0; tile < 4; ++tile) {
                acc[tile] = __builtin_amdgcn_mfma_f32_16x16x32_bf16(wi1f[c][tile], hb0, acc[tile], 0, 0, 0);
                acc[tile] = __builtin_amdgcn_mfma_f32_16x16x32_bf16(wh1f[c][tile], hb1, acc[tile], 0, 0, 0);
            }
        }
        __syncthreads();   // phase3 reads of h1frag done

        // ---- phase 4: layer-1 pointwise update (lane-local) ----
        {
            s16x4 hw;
            #pragma unroll
            for (int r = 0; r < 4; ++r) {
                float ig = sigmoidf_(acc[0][r]);
                float fg = sigmoidf_(acc[1][r]);
                float gg = tanhf_(acc[2][r]);
                float og = sigmoidf_(acc[3][r]);
                float cc = fg * c1v[r] + ig * gg;
                c1v[r] = cc;
                float hh = og * tanhf_(cc);
                hfin[r] = hh;
                hw[r] = (short)f2bf(hh);
            }
            *(s16x4*)&h1frag[fragoff] = hw;
        }
        // no barrier needed here: next phase1 touches only h0frag/w0lds/xlds
    }

    // ---- head: reuse w0lds as f32 scratch ----
    float* h1last  = (float*)w0lds;          // [16][128]
    float* hiddenL = ((float*)w0lds) + 2048; // [16][64]

    {   // every lane writes its 4 final h1 (f32, pre-quantization)
        f32x4 hv;
        hv[0] = hfin[0]; hv[1] = hfin[1]; hv[2] = hfin[2]; hv[3] = hfin[3];
        *(f32x4*)&h1last[n * HDIM + u0] = hv;
    }
    __syncthreads();

    #pragma unroll
    for (int rep = 0; rep < 2; ++rep) {
        int idx = tid + rep * 512;           // 1024 = 16 batch * 64 hidden
        int nn = idx >> 6, j = idx & 63;
        float s = b1[j];
        const float* wrow = W1 + j * HDIM;
        const float* hrow = h1last + nn * HDIM;
        #pragma unroll
        for (int k = 0; k < HDIM; k += 4) {
            f32x4 hv = *(const f32x4*)&hrow[k];
            f32x4 wv = *(const f32x4*)&wrow[k];
            s += hv[0]*wv[0] + hv[1]*wv[1] + hv[2]*wv[2] + hv[3]*wv[3];
        }
        hiddenL[nn * 64 + j] = fmaxf(s, 0.0f);
    }
    __syncthreads();

    if (tid < 128) {
        int nn = tid >> 3, cls = tid & 7;
        float s = b2[cls];
        const float* wrow = W2 + cls * 64;
        const float* hrow = hiddenL + nn * 64;
        #pragma unroll
        for (int k = 0; k < 64; k += 4) {
            f32x4 hv = *(const f32x4*)&hrow[k];
            f32x4 wv = *(const f32x4*)&wrow[k];
            s += hv[0]*wv[0] + hv[1]*wv[1] + hv[2]*wv[2] + hv[3]*wv[3];
        }
        out[(size_t)(b0 + nn) * 8 + cls] = s;
    }
}

extern "C" void kernel_launch(void* const* d_in, const int* in_sizes, int n_in,
                              void* d_out, int out_size, void* d_ws, size_t ws_size,
                              hipStream_t stream) {
    const float* x    = (const float*)d_in[0];
    const float* Wih0 = (const float*)d_in[1];
    const float* Whh0 = (const float*)d_in[2];
    const float* bih0 = (const float*)d_in[3];
    const float* bhh0 = (const float*)d_in[4];
    const float* Wih1 = (const float*)d_in[5];
    const float* Whh1 = (const float*)d_in[6];
    const float* bih1 = (const float*)d_in[7];
    const float* bhh1 = (const float*)d_in[8];
    const float* W1   = (const float*)d_in[9];
    const float* b1   = (const float*)d_in[10];
    const float* W2   = (const float*)d_in[11];
    const float* b2   = (const float*)d_in[12];
    float* outp = (float*)d_out;

    lstm_fused_kernel<<<128, 512, 0, stream>>>(
        x, Wih0, Whh0, bih0, bhh0, Wih1, Whh1, bih1, bhh1, W1, b1, W2, b2, outp);
}